// Round 1
// baseline (490.876 us; speedup 1.0000x reference)
//
#include <hip/hip_runtime.h>
#include <cstdint>
#include <cstddef>

// ---------------------------------------------------------------------------
// MS-Deformable Attention forward, MI355X / gfx950, fp32 baseline (round 1).
// B=4, L1=4096, Q_DIM=V_DIM=256, NH=8, NL=4, NP=4,
// LEVELS = (128,128),(64,64),(32,32),(16,16) -> L2=21760.
// Pipeline:
//   1) gemm_f32: v   = value @ Wv^T + bv, mask      (87040x256x256) -> ws
//   2) gemm_f32: off = query @ Wo^T + bo            (16384x256x256) -> ws
//   3) gemm_f32: la  = query @ Wa^T + ba            (16384x128x256) -> ws
//   4) softmax over 16 per (q,h)                    -> d_out[attn part]
//   5) sample: bilinear gather of v, attn-weighted  -> s in ws
//   6) gemm_f32: out = s @ Wout^T + bout            (16384x256x256) -> d_out
// ---------------------------------------------------------------------------

#define L1_LEN  4096
#define L2_LEN  21760
#define NHEAD   8
#define NLVL    4
#define NPT     4
#define BQ_TOT  (4 * L1_LEN)          // 16384 (b, l1) pairs

// ---------------------------------------------------------------------------
// Generic fp32 GEMM: C[M][N] = A[M][K] @ W[N][K]^T + bias[N], optional row
// mask (zero whole C row AFTER bias, matching reference where(mask,0,v)).
// Tiles: BM=128, BN=64, BK=16; 256 threads; 8x4 micro-tile per thread.
// M % 128 == 0, N % 64 == 0, K % 16 == 0 for all our shapes.
// ---------------------------------------------------------------------------
__global__ __launch_bounds__(256) void gemm_f32(
    const float* __restrict__ A, const float* __restrict__ W,
    const float* __restrict__ bias, float* __restrict__ C,
    int M, int N, int K, const unsigned char* __restrict__ mask)
{
    __shared__ float As[16][128];   // [k][m]
    __shared__ float Bs[16][64];    // [k][n]

    const int t  = threadIdx.x;
    const int bm = blockIdx.x, bn = blockIdx.y;

    // global->LDS load mapping
    const int arow = t >> 1;             // 0..127
    const int acol = (t & 1) * 8;        // 0 or 8
    const int brow = t >> 2;             // 0..63
    const int bcol = (t & 3) * 4;        // 0,4,8,12
    const float* Ap = A + (size_t)(bm * 128 + arow) * K + acol;
    const float* Wp = W + (size_t)(bn * 64 + brow) * K + bcol;

    // compute mapping: 16x16 thread grid, 8 rows x 4 cols each
    const int tm = (t & 15) * 8;         // 0..120
    const int tn = (t >> 4) * 4;         // 0..60

    float acc[8][4] = {};

    for (int k0 = 0; k0 < K; k0 += 16) {
        const float4 a0 = *(const float4*)(Ap + k0);
        const float4 a1 = *(const float4*)(Ap + k0 + 4);
        const float4 b0 = *(const float4*)(Wp + k0);
        __syncthreads();
        As[acol + 0][arow] = a0.x; As[acol + 1][arow] = a0.y;
        As[acol + 2][arow] = a0.z; As[acol + 3][arow] = a0.w;
        As[acol + 4][arow] = a1.x; As[acol + 5][arow] = a1.y;
        As[acol + 6][arow] = a1.z; As[acol + 7][arow] = a1.w;
        Bs[bcol + 0][brow] = b0.x; Bs[bcol + 1][brow] = b0.y;
        Bs[bcol + 2][brow] = b0.z; Bs[bcol + 3][brow] = b0.w;
        __syncthreads();
#pragma unroll
        for (int k = 0; k < 16; ++k) {
            const float4 av0 = *(const float4*)&As[k][tm];
            const float4 av1 = *(const float4*)&As[k][tm + 4];
            const float4 bv0 = *(const float4*)&Bs[k][tn];
            const float am[8] = {av0.x, av0.y, av0.z, av0.w,
                                 av1.x, av1.y, av1.z, av1.w};
            const float bnv[4] = {bv0.x, bv0.y, bv0.z, bv0.w};
#pragma unroll
            for (int i = 0; i < 8; ++i)
#pragma unroll
                for (int j = 0; j < 4; ++j)
                    acc[i][j] += am[i] * bnv[j];
        }
    }

    const int col = bn * 64 + tn;
    const float4 bb = *(const float4*)(bias + col);
#pragma unroll
    for (int i = 0; i < 8; ++i) {
        const int row = bm * 128 + tm + i;
        float mz = 1.0f;
        if (mask != nullptr && mask[row]) mz = 0.0f;
        float4 r;
        r.x = (acc[i][0] + bb.x) * mz;
        r.y = (acc[i][1] + bb.y) * mz;
        r.z = (acc[i][2] + bb.z) * mz;
        r.w = (acc[i][3] + bb.w) * mz;
        *(float4*)(C + (size_t)row * N + col) = r;
    }
}

// ---------------------------------------------------------------------------
// Softmax over the 16 (NL*NP) logits per (b,q,h). One thread per (b,q,h).
// ---------------------------------------------------------------------------
__global__ __launch_bounds__(256) void softmax_kernel(
    const float* __restrict__ logits, float* __restrict__ attn, int total)
{
    const int i = blockIdx.x * blockDim.x + threadIdx.x;
    if (i >= total) return;
    const float4* p = (const float4*)(logits + (size_t)i * 16);
    const float4 v0 = p[0], v1 = p[1], v2 = p[2], v3 = p[3];
    float v[16] = {v0.x, v0.y, v0.z, v0.w, v1.x, v1.y, v1.z, v1.w,
                   v2.x, v2.y, v2.z, v2.w, v3.x, v3.y, v3.z, v3.w};
    float m = v[0];
#pragma unroll
    for (int j = 1; j < 16; ++j) m = fmaxf(m, v[j]);
    float s = 0.0f;
#pragma unroll
    for (int j = 0; j < 16; ++j) { v[j] = __expf(v[j] - m); s += v[j]; }
    const float inv = 1.0f / s;
    float4* o = (float4*)(attn + (size_t)i * 16);
    o[0] = make_float4(v[0] * inv, v[1] * inv, v[2] * inv, v[3] * inv);
    o[1] = make_float4(v[4] * inv, v[5] * inv, v[6] * inv, v[7] * inv);
    o[2] = make_float4(v[8] * inv, v[9] * inv, v[10] * inv, v[11] * inv);
    o[3] = make_float4(v[12] * inv, v[13] * inv, v[14] * inv, v[15] * inv);
}

// ---------------------------------------------------------------------------
// Bilinear sampling + attention-weighted accumulation.
// Block = 256 threads = 8 queries x (8 heads x 4 channel-groups of 8).
// Each thread accumulates 8 channels of s[b,q,h,:] over 4 levels x 4 points
// x 4 taps. Loads per tap: 2x float4 (32 B), contiguous 128 B across the 4
// lanes sharing (q,h). v (89 MB) is L3-resident.
// ---------------------------------------------------------------------------
__global__ __launch_bounds__(256) void sample_kernel(
    const float* __restrict__ v,      // (B, L2, 256), ch = h*32+c
    const float* __restrict__ offm,   // (BQ, 256) = (q, h,L,P,2)
    const float* __restrict__ attn,   // (BQ, 128) = (q, h, L*4+P)
    const float* __restrict__ ref,    // (BQ, 4) cx,cy,sx,sy
    const float* __restrict__ vr,     // (B, 4, 2) valid ratios
    const int*   __restrict__ vshape, // (4,2) H,W
    const int*   __restrict__ vstart, // (4,)
    float* __restrict__ sout)         // (BQ, 256)
{
    const int t  = threadIdx.x;
    const int q  = blockIdx.x * 8 + (t >> 5);
    const int h  = (t >> 2) & 7;
    const int c0 = (t & 3) * 8;
    const int b  = q >> 12;            // / L1_LEN

    const float4 rw = *(const float4*)(ref + (size_t)q * 4);
    const float* op = offm + (size_t)q * 256 + h * 32;
    const float* ap = attn + (size_t)q * 128 + h * 16;

    float acc[8] = {};

#pragma unroll
    for (int l = 0; l < NLVL; ++l) {
        const int H = vshape[l * 2 + 0];
        const int W = vshape[l * 2 + 1];
        const int start = vstart[l];
        const float vrx = vr[(b * 4 + l) * 2 + 0];
        const float vry = vr[(b * 4 + l) * 2 + 1];
        const float fW = (float)W, fH = (float)H;
        const float* vb = v + ((size_t)b * L2_LEN + start) * 256 + h * 32 + c0;
#pragma unroll
        for (int p = 0; p < NPT; ++p) {
            const float a  = ap[l * 4 + p];
            const float ox = op[(l * 4 + p) * 2 + 0];
            const float oy = op[(l * 4 + p) * 2 + 1];
            const float x = (rw.x + ox * 0.125f * rw.z) * vrx * fW - 0.5f;
            const float y = (rw.y + oy * 0.125f * rw.w) * vry * fH - 0.5f;
            const float x0f = floorf(x), y0f = floorf(y);
            const float fx = x - x0f, fy = y - y0f;
            const int x0 = (int)x0f, y0 = (int)y0f;
#pragma unroll
            for (int dy = 0; dy < 2; ++dy) {
                const int yi = y0 + dy;
                const float wy = dy ? fy : 1.0f - fy;
                const bool vy = (yi >= 0) && (yi < H);
                const int yc = min(max(yi, 0), H - 1);
#pragma unroll
                for (int dx = 0; dx < 2; ++dx) {
                    const int xi = x0 + dx;
                    const float wx = dx ? fx : 1.0f - fx;
                    const bool vx = (xi >= 0) && (xi < W);
                    const int xc = min(max(xi, 0), W - 1);
                    float w = wx * wy * a;
                    if (!(vx && vy)) w = 0.0f;
                    const float* g = vb + (size_t)(yc * W + xc) * 256;
                    const float4 g0 = *(const float4*)(g);
                    const float4 g1 = *(const float4*)(g + 4);
                    acc[0] += w * g0.x; acc[1] += w * g0.y;
                    acc[2] += w * g0.z; acc[3] += w * g0.w;
                    acc[4] += w * g1.x; acc[5] += w * g1.y;
                    acc[6] += w * g1.z; acc[7] += w * g1.w;
                }
            }
        }
    }

    float4* so = (float4*)(sout + (size_t)q * 256 + h * 32 + c0);
    so[0] = make_float4(acc[0], acc[1], acc[2], acc[3]);
    so[1] = make_float4(acc[4], acc[5], acc[6], acc[7]);
}

// ---------------------------------------------------------------------------
extern "C" void kernel_launch(void* const* d_in, const int* in_sizes, int n_in,
                              void* d_out, int out_size, void* d_ws, size_t ws_size,
                              hipStream_t stream)
{
    const float*         query    = (const float*)d_in[0];
    const float*         value    = (const float*)d_in[1];
    const int*           v_shape  = (const int*)d_in[2];
    const unsigned char* v_mask   = (const unsigned char*)d_in[3];
    const int*           v_start  = (const int*)d_in[4];
    const float*         v_ratios = (const float*)d_in[5];
    const float*         ref_w    = (const float*)d_in[6];
    const float*         Wo       = (const float*)d_in[7];
    const float*         bo       = (const float*)d_in[8];
    const float*         Wa       = (const float*)d_in[9];
    const float*         ba       = (const float*)d_in[10];
    const float*         Wv       = (const float*)d_in[11];
    const float*         bv       = (const float*)d_in[12];
    const float*         Wout     = (const float*)d_in[13];
    const float*         bout     = (const float*)d_in[14];

    float* out      = (float*)d_out;                       // (16384, 256)
    float* attn_out = out + (size_t)BQ_TOT * 256;          // (16384, 128)

    float* ws      = (float*)d_ws;
    float* off_ws  = ws;                                   // 16384*256
    float* loga_ws = off_ws + (size_t)BQ_TOT * 256;        // 16384*128
    float* v_ws    = loga_ws + (size_t)BQ_TOT * 128;       // 87040*256
    float* s_ws    = v_ws + (size_t)4 * L2_LEN * 256;      // 16384*256

    const int MV = 4 * L2_LEN;   // 87040
    const int MQ = BQ_TOT;       // 16384

    // 1) value projection (+mask)
    gemm_f32<<<dim3(MV / 128, 256 / 64), 256, 0, stream>>>(
        value, Wv, bv, v_ws, MV, 256, 256, v_mask);
    // 2) offset projection
    gemm_f32<<<dim3(MQ / 128, 256 / 64), 256, 0, stream>>>(
        query, Wo, bo, off_ws, MQ, 256, 256, nullptr);
    // 3) attention logits
    gemm_f32<<<dim3(MQ / 128, 128 / 64), 256, 0, stream>>>(
        query, Wa, ba, loga_ws, MQ, 128, 256, nullptr);
    // 4) softmax -> attn output (also consumed by sampling)
    softmax_kernel<<<(MQ * NHEAD + 255) / 256, 256, 0, stream>>>(
        loga_ws, attn_out, MQ * NHEAD);
    // 5) deformable sampling + attention weighting
    sample_kernel<<<MQ / 8, 256, 0, stream>>>(
        v_ws, off_ws, attn_out, ref_w, v_ratios, v_shape, v_start, s_ws);
    // 6) output projection
    gemm_f32<<<dim3(MQ / 128, 256 / 64), 256, 0, stream>>>(
        s_ws, Wout, bout, out, MQ, 256, 256, nullptr);
}

// Round 2
// 391.773 us; speedup vs baseline: 1.2530x; 1.2530x over previous
//
#include <hip/hip_runtime.h>
#include <cstdint>
#include <cstddef>

// ---------------------------------------------------------------------------
// MS-Deformable Attention forward, MI355X / gfx950 — round 2.
// GEMMs now use bf16 MFMA (16x16x32) with 3-term hi/lo split for ~fp32
// accuracy at matrix-core rate:
//   A = Ah + Al (bf16),  W = Wh + Wl (bf16),  A@W ~= AhWh + AhWl + AlWh
// (dropped AlWl term ~2^-16 relative).
// Pipeline:
//   1) gemm_split: v    = value @ Wv^T + bv, mask       (87040x256x256)
//   2) gemm_split: [off|logits] = query @ [Wo;Wa]^T + b (16384x384x256, fused)
//   3) softmax over 16 per (q,h)  -> d_out[attn]
//   4) sample: bilinear gather of v, attn-weighted      (unchanged fp32)
//   5) gemm_split: out  = s @ Wout^T + bout             (16384x256x256)
// ---------------------------------------------------------------------------

#define L1_LEN  4096
#define L2_LEN  21760
#define BQ_TOT  16384
#define KDIM    256
#define NLVL    4
#define NPT     4

typedef __attribute__((ext_vector_type(8))) short short8;   // 8 bf16 = 1 MFMA operand
typedef __attribute__((ext_vector_type(4))) short short4v;  // 4 bf16 (8 B)
typedef __attribute__((ext_vector_type(4))) float f32x4;    // MFMA accumulator

__device__ __forceinline__ unsigned short f2bf(float f) {   // RNE fp32->bf16
    unsigned u = __builtin_bit_cast(unsigned, f);
    u += 0x7fffu + ((u >> 16) & 1u);
    return (unsigned short)(u >> 16);
}
__device__ __forceinline__ float bf2f(unsigned short s) {
    return __builtin_bit_cast(float, (unsigned)s << 16);
}

// ---------------------------------------------------------------------------
// C[row][ldC] tile (bm,bn) = A[128 rows] @ Wsel[128 cols]^T + bias, K=256.
// Col-tile source select: nb = bn*128 < n_split ? (W0,b0) : (W1,b1) shifted —
// lets one launch fuse two weight matrices stacked along N (Wo ; Wa).
// LDS holds Ah/Al/Wh/Wl tiles in FRAGMENT-MAJOR order:
//   slot(r,k) = (r>>4)*512 + ((r&15) + 16*(k>>3))*8 + (k&7)   [shorts]
// so a wave's MFMA fragment read is ds_read_b128 at (fragbase + lane*16B):
// linear across lanes -> bank-conflict-free by construction.
// 256 threads = 4 waves (2x2), each wave owns a 64x64 output sub-tile.
// ---------------------------------------------------------------------------
__global__ __launch_bounds__(256, 2) void gemm_split_bf16(
    const float* __restrict__ A,
    const float* __restrict__ W0, const float* __restrict__ W1,
    const float* __restrict__ b0, const float* __restrict__ b1,
    int n_split, float* __restrict__ C, int ldC,
    const unsigned char* __restrict__ mask)
{
    __shared__ short Ah[4096], Al[4096], Bh[4096], Bl[4096];  // 8 KiB each

    const int t    = threadIdx.x;
    const int bm   = blockIdx.x, bn = blockIdx.y;
    const int lane = t & 63;
    const int wid  = t >> 6;
    const int wm   = wid >> 1, wn = wid & 1;

    const int nb = bn * 128;
    const float* Wt; const float* bt;
    if (nb < n_split) { Wt = W0 + (size_t)nb * KDIM;             bt = b0 + nb; }
    else              { Wt = W1 + (size_t)(nb - n_split) * KDIM; bt = b1 + (nb - n_split); }

    const float* Ag = A + (size_t)bm * 128 * KDIM;

    f32x4 acc[4][4] = {};

    for (int kk = 0; kk < KDIM; kk += 32) {
        // -- global loads: tile-linear mapping, wave reads 1 KiB contiguous
        float4 av[4], wv[4];
#pragma unroll
        for (int i = 0; i < 4; ++i) {
            const int o = t * 4 + i * 1024;        // float index in 128x32 tile
            const int r = o >> 5, c = o & 31;
            av[i] = *(const float4*)(Ag + (size_t)r * KDIM + kk + c);
            wv[i] = *(const float4*)(Wt + (size_t)r * KDIM + kk + c);
        }
        __syncthreads();   // prior iteration's frag reads done
#pragma unroll
        for (int i = 0; i < 4; ++i) {
            const int o = t * 4 + i * 1024;
            const int r = o >> 5, c = o & 31;
            const int slot = (r >> 4) * 512 + ((r & 15) + 16 * (c >> 3)) * 8 + (c & 7);
            {
                const unsigned short h0 = f2bf(av[i].x), h1 = f2bf(av[i].y),
                                     h2 = f2bf(av[i].z), h3 = f2bf(av[i].w);
                *(short4v*)&Ah[slot] = short4v{(short)h0, (short)h1, (short)h2, (short)h3};
                *(short4v*)&Al[slot] = short4v{
                    (short)f2bf(av[i].x - bf2f(h0)), (short)f2bf(av[i].y - bf2f(h1)),
                    (short)f2bf(av[i].z - bf2f(h2)), (short)f2bf(av[i].w - bf2f(h3))};
            }
            {
                const unsigned short h0 = f2bf(wv[i].x), h1 = f2bf(wv[i].y),
                                     h2 = f2bf(wv[i].z), h3 = f2bf(wv[i].w);
                *(short4v*)&Bh[slot] = short4v{(short)h0, (short)h1, (short)h2, (short)h3};
                *(short4v*)&Bl[slot] = short4v{
                    (short)f2bf(wv[i].x - bf2f(h0)), (short)f2bf(wv[i].y - bf2f(h1)),
                    (short)f2bf(wv[i].z - bf2f(h2)), (short)f2bf(wv[i].w - bf2f(h3))};
            }
        }
        __syncthreads();

        // -- fragment reads (linear, conflict-free) + 48 MFMAs
        short8 ah[4], al[4], bh[4], bl[4];
#pragma unroll
        for (int x = 0; x < 4; ++x) {
            ah[x] = ((const short8*)Ah)[(wm * 4 + x) * 64 + lane];
            al[x] = ((const short8*)Al)[(wm * 4 + x) * 64 + lane];
            bh[x] = ((const short8*)Bh)[(wn * 4 + x) * 64 + lane];
            bl[x] = ((const short8*)Bl)[(wn * 4 + x) * 64 + lane];
        }
#pragma unroll
        for (int m = 0; m < 4; ++m)
#pragma unroll
            for (int n = 0; n < 4; ++n) {
                acc[m][n] = __builtin_amdgcn_mfma_f32_16x16x32_bf16(ah[m], bh[n], acc[m][n], 0, 0, 0);
                acc[m][n] = __builtin_amdgcn_mfma_f32_16x16x32_bf16(ah[m], bl[n], acc[m][n], 0, 0, 0);
                acc[m][n] = __builtin_amdgcn_mfma_f32_16x16x32_bf16(al[m], bh[n], acc[m][n], 0, 0, 0);
            }
    }

    // -- epilogue: C/D layout col=lane&15, row=(lane>>4)*4+reg  [m89-verified]
    const int cb = nb + wn * 64;
    const int rb = bm * 128 + wm * 64;
    const int cl = lane & 15, rl = (lane >> 4) * 4;
    float bias_n[4];
#pragma unroll
    for (int n = 0; n < 4; ++n) bias_n[n] = bt[wn * 64 + n * 16 + cl];
#pragma unroll
    for (int m = 0; m < 4; ++m) {
        float mz[4];
#pragma unroll
        for (int r = 0; r < 4; ++r) {
            const int row = rb + m * 16 + rl + r;
            mz[r] = (mask != nullptr && mask[row]) ? 0.0f : 1.0f;
        }
#pragma unroll
        for (int n = 0; n < 4; ++n) {
            const int col = cb + n * 16 + cl;
#pragma unroll
            for (int r = 0; r < 4; ++r) {
                const int row = rb + m * 16 + rl + r;
                C[(size_t)row * ldC + col] = (acc[m][n][r] + bias_n[n]) * mz[r];
            }
        }
    }
}

// ---------------------------------------------------------------------------
// Softmax over 16 (NL*NP) logits per (b,q,h). Logits live at
// base + q*stride + h*16 (stride=384: packed behind offsets in fused buffer).
// ---------------------------------------------------------------------------
__global__ __launch_bounds__(256) void softmax_kernel(
    const float* __restrict__ logits, int stride,
    float* __restrict__ attn, int total)
{
    const int i = blockIdx.x * blockDim.x + threadIdx.x;
    if (i >= total) return;
    const int q = i >> 3, h = i & 7;
    const float4* p = (const float4*)(logits + (size_t)q * stride + h * 16);
    const float4 v0 = p[0], v1 = p[1], v2 = p[2], v3 = p[3];
    float v[16] = {v0.x, v0.y, v0.z, v0.w, v1.x, v1.y, v1.z, v1.w,
                   v2.x, v2.y, v2.z, v2.w, v3.x, v3.y, v3.z, v3.w};
    float m = v[0];
#pragma unroll
    for (int j = 1; j < 16; ++j) m = fmaxf(m, v[j]);
    float s = 0.0f;
#pragma unroll
    for (int j = 0; j < 16; ++j) { v[j] = __expf(v[j] - m); s += v[j]; }
    const float inv = 1.0f / s;
    float4* o = (float4*)(attn + (size_t)i * 16);
    o[0] = make_float4(v[0] * inv, v[1] * inv, v[2] * inv, v[3] * inv);
    o[1] = make_float4(v[4] * inv, v[5] * inv, v[6] * inv, v[7] * inv);
    o[2] = make_float4(v[8] * inv, v[9] * inv, v[10] * inv, v[11] * inv);
    o[3] = make_float4(v[12] * inv, v[13] * inv, v[14] * inv, v[15] * inv);
}

// ---------------------------------------------------------------------------
// Bilinear sampling + attention-weighted accumulation (fp32, unchanged except
// offset-buffer stride). Block = 8 queries x (8 heads x 4 ch-groups of 8).
// ---------------------------------------------------------------------------
__global__ __launch_bounds__(256) void sample_kernel(
    const float* __restrict__ v,      // (B, L2, 256)
    const float* __restrict__ offm,   // (BQ, off_stride), cols 0..255 = offsets
    int off_stride,
    const float* __restrict__ attn,   // (BQ, 128)
    const float* __restrict__ ref,    // (BQ, 4)
    const float* __restrict__ vr,     // (B, 4, 2)
    const int*   __restrict__ vshape, // (4,2)
    const int*   __restrict__ vstart, // (4,)
    float* __restrict__ sout)         // (BQ, 256)
{
    const int t  = threadIdx.x;
    const int q  = blockIdx.x * 8 + (t >> 5);
    const int h  = (t >> 2) & 7;
    const int c0 = (t & 3) * 8;
    const int b  = q >> 12;

    const float4 rw = *(const float4*)(ref + (size_t)q * 4);
    const float* op = offm + (size_t)q * off_stride + h * 32;
    const float* ap = attn + (size_t)q * 128 + h * 16;

    float acc[8] = {};

#pragma unroll
    for (int l = 0; l < NLVL; ++l) {
        const int H = vshape[l * 2 + 0];
        const int W = vshape[l * 2 + 1];
        const int start = vstart[l];
        const float vrx = vr[(b * 4 + l) * 2 + 0];
        const float vry = vr[(b * 4 + l) * 2 + 1];
        const float fW = (float)W, fH = (float)H;
        const float* vb = v + ((size_t)b * L2_LEN + start) * 256 + h * 32 + c0;
#pragma unroll
        for (int p = 0; p < NPT; ++p) {
            const float a  = ap[l * 4 + p];
            const float ox = op[(l * 4 + p) * 2 + 0];
            const float oy = op[(l * 4 + p) * 2 + 1];
            const float x = (rw.x + ox * 0.125f * rw.z) * vrx * fW - 0.5f;
            const float y = (rw.y + oy * 0.125f * rw.w) * vry * fH - 0.5f;
            const float x0f = floorf(x), y0f = floorf(y);
            const float fx = x - x0f, fy = y - y0f;
            const int x0 = (int)x0f, y0 = (int)y0f;
#pragma unroll
            for (int dy = 0; dy < 2; ++dy) {
                const int yi = y0 + dy;
                const float wy = dy ? fy : 1.0f - fy;
                const bool vy = (yi >= 0) && (yi < H);
                const int yc = min(max(yi, 0), H - 1);
#pragma unroll
                for (int dx = 0; dx < 2; ++dx) {
                    const int xi = x0 + dx;
                    const float wx = dx ? fx : 1.0f - fx;
                    const bool vx = (xi >= 0) && (xi < W);
                    const int xc = min(max(xi, 0), W - 1);
                    float w = wx * wy * a;
                    if (!(vx && vy)) w = 0.0f;
                    const float* g = vb + (size_t)(yc * W + xc) * 256;
                    const float4 g0 = *(const float4*)(g);
                    const float4 g1 = *(const float4*)(g + 4);
                    acc[0] += w * g0.x; acc[1] += w * g0.y;
                    acc[2] += w * g0.z; acc[3] += w * g0.w;
                    acc[4] += w * g1.x; acc[5] += w * g1.y;
                    acc[6] += w * g1.z; acc[7] += w * g1.w;
                }
            }
        }
    }

    float4* so = (float4*)(sout + (size_t)q * 256 + h * 32 + c0);
    so[0] = make_float4(acc[0], acc[1], acc[2], acc[3]);
    so[1] = make_float4(acc[4], acc[5], acc[6], acc[7]);
}

// ---------------------------------------------------------------------------
extern "C" void kernel_launch(void* const* d_in, const int* in_sizes, int n_in,
                              void* d_out, int out_size, void* d_ws, size_t ws_size,
                              hipStream_t stream)
{
    const float*         query    = (const float*)d_in[0];
    const float*         value    = (const float*)d_in[1];
    const int*           v_shape  = (const int*)d_in[2];
    const unsigned char* v_mask   = (const unsigned char*)d_in[3];
    const int*           v_start  = (const int*)d_in[4];
    const float*         v_ratios = (const float*)d_in[5];
    const float*         ref_w    = (const float*)d_in[6];
    const float*         Wo       = (const float*)d_in[7];
    const float*         bo       = (const float*)d_in[8];
    const float*         Wa       = (const float*)d_in[9];
    const float*         ba       = (const float*)d_in[10];
    const float*         Wv       = (const float*)d_in[11];
    const float*         bv       = (const float*)d_in[12];
    const float*         Wout     = (const float*)d_in[13];
    const float*         bout     = (const float*)d_in[14];

    float* out      = (float*)d_out;                       // (16384, 256)
    float* attn_out = out + (size_t)BQ_TOT * 256;          // (16384, 128)

    float* qp_ws = (float*)d_ws;                           // (16384, 384): off|logits
    float* v_ws  = qp_ws + (size_t)BQ_TOT * 384;           // (87040, 256)
    float* s_ws  = v_ws + (size_t)4 * L2_LEN * 256;        // (16384, 256)

    // 1) value projection (+mask): N=256 -> 2 col tiles, both from Wv
    gemm_split_bf16<<<dim3(87040 / 128, 2), 256, 0, stream>>>(
        value, Wv, Wv, bv, bv, 256, v_ws, 256, v_mask);
    // 2) fused offset+logits projection: N=384 = [Wo(256) ; Wa(128)]
    gemm_split_bf16<<<dim3(BQ_TOT / 128, 3), 256, 0, stream>>>(
        query, Wo, Wa, bo, ba, 256, qp_ws, 384, nullptr);
    // 3) softmax on logits (cols 256..383 of fused buffer)
    softmax_kernel<<<(BQ_TOT * 8 + 255) / 256, 256, 0, stream>>>(
        qp_ws + 256, 384, attn_out, BQ_TOT * 8);
    // 4) deformable sampling + attention weighting
    sample_kernel<<<BQ_TOT / 8, 256, 0, stream>>>(
        v_ws, qp_ws, 384, attn_out, ref_w, v_ratios, v_shape, v_start, s_ws);
    // 5) output projection
    gemm_split_bf16<<<dim3(BQ_TOT / 128, 2), 256, 0, stream>>>(
        s_ws, Wout, Wout, bout, bout, 256, out, 256, nullptr);
}

// Round 3
// 292.799 us; speedup vs baseline: 1.6765x; 1.3380x over previous
//
#include <hip/hip_runtime.h>
#include <cstdint>
#include <cstddef>

// ---------------------------------------------------------------------------
// MS-Deformable Attention forward, MI355X / gfx950 — round 3.
// All GEMMs: single-term fp16 MFMA (16x16x32_f16), inputs pre-converted to
// fp16 once, staged via global_load_lds(16B) into fragment-major LDS
// (lane-linear -> conflict-free). v stored fp16 for the sampler (halves
// gather bytes); sampler: 4 queries/block (L1 locality) + batched tap loads.
// Error budget: fp16 rel 2^-11 -> v err ~7e-4, out err ~2e-3 (absmax ~0.004
// baseline was reference-side; expect <= 0.008).
// ---------------------------------------------------------------------------

#define L2_LEN 21760
#define BQ_TOT 16384
#define KD     256

typedef __attribute__((ext_vector_type(8))) _Float16 half8;
typedef __attribute__((ext_vector_type(4))) float    f32x4;

__device__ __forceinline__ void glds16(const _Float16* g, _Float16* l) {
    __builtin_amdgcn_global_load_lds(
        (const __attribute__((address_space(1))) void*)g,
        (__attribute__((address_space(3))) void*)l, 16, 0, 0);
}

// ---------------------------------------------------------------------------
// fp32 -> fp16 streaming convert (8 elements/thread/iter).
// ---------------------------------------------------------------------------
__global__ __launch_bounds__(256) void cvt_f32_f16(
    const float* __restrict__ in, _Float16* __restrict__ out, int n8)
{
    for (int i = blockIdx.x * 256 + threadIdx.x; i < n8; i += gridDim.x * 256) {
        const float4 f0 = ((const float4*)in)[i * 2];
        const float4 f1 = ((const float4*)in)[i * 2 + 1];
        half8 h;
        h[0] = (_Float16)f0.x; h[1] = (_Float16)f0.y;
        h[2] = (_Float16)f0.z; h[3] = (_Float16)f0.w;
        h[4] = (_Float16)f1.x; h[5] = (_Float16)f1.y;
        h[6] = (_Float16)f1.z; h[7] = (_Float16)f1.w;
        ((half8*)out)[i] = h;
    }
}

// ---------------------------------------------------------------------------
// Pack [Wv | Wo | Wa | Wout] -> Wp fp16 (896 x 256) and biases -> bp fp32.
// grid = 112 x 256 covers 28672 8-element chunks.
// ---------------------------------------------------------------------------
__global__ __launch_bounds__(256) void cvt_weights(
    const float* __restrict__ Wv, const float* __restrict__ Wo,
    const float* __restrict__ Wa, const float* __restrict__ Wout,
    const float* __restrict__ bv, const float* __restrict__ bo,
    const float* __restrict__ ba, const float* __restrict__ bout,
    _Float16* __restrict__ Wp, float* __restrict__ bp)
{
    const int gid = blockIdx.x * 256 + threadIdx.x;      // 0..28671
    const float* src; int off8;
    if      (gid <  8192) { src = Wv;   off8 = gid;         }
    else if (gid < 16384) { src = Wo;   off8 = gid -  8192; }
    else if (gid < 20480) { src = Wa;   off8 = gid - 16384; }
    else                  { src = Wout; off8 = gid - 20480; }
    const float4 f0 = ((const float4*)src)[off8 * 2];
    const float4 f1 = ((const float4*)src)[off8 * 2 + 1];
    half8 h;
    h[0] = (_Float16)f0.x; h[1] = (_Float16)f0.y;
    h[2] = (_Float16)f0.z; h[3] = (_Float16)f0.w;
    h[4] = (_Float16)f1.x; h[5] = (_Float16)f1.y;
    h[6] = (_Float16)f1.z; h[7] = (_Float16)f1.w;
    ((half8*)Wp)[gid] = h;
    if (gid < 896) {
        float b;
        if      (gid < 256) b = bv[gid];
        else if (gid < 512) b = bo[gid - 256];
        else if (gid < 640) b = ba[gid - 512];
        else                b = bout[gid - 640];
        bp[gid] = b;
    }
}

// ---------------------------------------------------------------------------
// C[128x128 tile] = A[M][256]fp16 @ Wp[rows wrow0+][256]fp16 ^T + bp, K=256.
// 256 thr = 4 waves (2x2), wave owns 64x64. LDS fragment-major:
//   chunk u (16B) <-> (r = (u>>6)*16 + (u&15), c8 = (u>>4)&3)
// so frag f = chunks [f*64, f*64+64), read at chunk f*64+lane (lane-linear).
// Staging: 4 x global_load_lds(16B) per wave per K-step (2 A + 2 B chunks).
// OUT_F16: fp16 C + row mask (vproj); else fp32 C.
// ---------------------------------------------------------------------------
template<bool OUT_F16>
__global__ __launch_bounds__(256) void gemm_f16(
    const _Float16* __restrict__ A, const _Float16* __restrict__ Wp,
    const float* __restrict__ bp, int wrow0,
    void* __restrict__ Cv, int ldC, const unsigned char* __restrict__ mask)
{
    __shared__ _Float16 As[4096];   // 8 KiB
    __shared__ _Float16 Bs[4096];   // 8 KiB

    const int t = threadIdx.x, lane = t & 63, wid = t >> 6;
    const int wm = wid >> 1, wn = wid & 1;
    const int bm = blockIdx.x, bn = blockIdx.y;

    // per-lane global source for the wave's 2 chunks of each matrix
    const int u0 = wid * 128 + lane;
    const int u1 = u0 + 64;
    const int ra0 = ((u0 >> 6) << 4) + (u0 & 15), ca0 = ((u0 >> 4) & 3) * 8;
    const int ra1 = ((u1 >> 6) << 4) + (u1 & 15), ca1 = ((u1 >> 4) & 3) * 8;
    const _Float16* Ag0 = A + (size_t)(bm * 128 + ra0) * KD + ca0;
    const _Float16* Ag1 = A + (size_t)(bm * 128 + ra1) * KD + ca1;
    const _Float16* Wg0 = Wp + (size_t)(wrow0 + bn * 128 + ra0) * KD + ca0;
    const _Float16* Wg1 = Wp + (size_t)(wrow0 + bn * 128 + ra1) * KD + ca1;
    _Float16* Ad0 = &As[wid * 1024];
    _Float16* Ad1 = &As[wid * 1024 + 512];
    _Float16* Bd0 = &Bs[wid * 1024];
    _Float16* Bd1 = &Bs[wid * 1024 + 512];

    f32x4 acc[4][4] = {};

    for (int kk = 0; kk < KD; kk += 32) {
        glds16(Ag0 + kk, Ad0);
        glds16(Ag1 + kk, Ad1);
        glds16(Wg0 + kk, Bd0);
        glds16(Wg1 + kk, Bd1);
        __syncthreads();                       // drains vmcnt (lds-DMA) too
        half8 ah[4], bh[4];
#pragma unroll
        for (int x = 0; x < 4; ++x) {
            ah[x] = ((const half8*)As)[(wm * 4 + x) * 64 + lane];
            bh[x] = ((const half8*)Bs)[(wn * 4 + x) * 64 + lane];
        }
#pragma unroll
        for (int m = 0; m < 4; ++m)
#pragma unroll
            for (int n = 0; n < 4; ++n)
                acc[m][n] = __builtin_amdgcn_mfma_f32_16x16x32_f16(
                    ah[m], bh[n], acc[m][n], 0, 0, 0);
        __syncthreads();                       // frag reads done before overwrite
    }

    // epilogue: C/D layout col=lane&15, row=(lane>>4)*4+reg (m89-verified)
    const int rb = bm * 128 + wm * 64, cb = bn * 128 + wn * 64;
    const int cl = lane & 15, rl = (lane >> 4) * 4;
    float bias_n[4];
#pragma unroll
    for (int n = 0; n < 4; ++n) bias_n[n] = bp[wrow0 + cb + n * 16 + cl];
#pragma unroll
    for (int m = 0; m < 4; ++m) {
        float mz[4];
#pragma unroll
        for (int r = 0; r < 4; ++r) {
            const int row = rb + m * 16 + rl + r;
            mz[r] = (mask != nullptr && mask[row]) ? 0.0f : 1.0f;
        }
#pragma unroll
        for (int n = 0; n < 4; ++n) {
            const int col = cb + n * 16 + cl;
#pragma unroll
            for (int r = 0; r < 4; ++r) {
                const int row = rb + m * 16 + rl + r;
                const float val = (acc[m][n][r] + bias_n[n]) * mz[r];
                if (OUT_F16) ((_Float16*)Cv)[(size_t)row * ldC + col] = (_Float16)val;
                else         ((float*)Cv)[(size_t)row * ldC + col] = val;
            }
        }
    }
}

// ---------------------------------------------------------------------------
// Softmax over 16 logits per (b,q,h); logits at qp + q*384 + 256 + h*16.
// ---------------------------------------------------------------------------
__global__ __launch_bounds__(256) void softmax_kernel(
    const float* __restrict__ logits, int stride,
    float* __restrict__ attn, int total)
{
    const int i = blockIdx.x * blockDim.x + threadIdx.x;
    if (i >= total) return;
    const int q = i >> 3, h = i & 7;
    const float4* p = (const float4*)(logits + (size_t)q * stride + h * 16);
    const float4 v0 = p[0], v1 = p[1], v2 = p[2], v3 = p[3];
    float v[16] = {v0.x, v0.y, v0.z, v0.w, v1.x, v1.y, v1.z, v1.w,
                   v2.x, v2.y, v2.z, v2.w, v3.x, v3.y, v3.z, v3.w};
    float m = v[0];
#pragma unroll
    for (int j = 1; j < 16; ++j) m = fmaxf(m, v[j]);
    float s = 0.0f;
#pragma unroll
    for (int j = 0; j < 16; ++j) { v[j] = __expf(v[j] - m); s += v[j]; }
    const float inv = 1.0f / s;
    float4* o = (float4*)(attn + (size_t)i * 16);
    o[0] = make_float4(v[0] * inv, v[1] * inv, v[2] * inv, v[3] * inv);
    o[1] = make_float4(v[4] * inv, v[5] * inv, v[6] * inv, v[7] * inv);
    o[2] = make_float4(v[8] * inv, v[9] * inv, v[10] * inv, v[11] * inv);
    o[3] = make_float4(v[12] * inv, v[13] * inv, v[14] * inv, v[15] * inv);
}

// ---------------------------------------------------------------------------
// Bilinear sampling + attention weighting, v fp16.
// Block 128 thr = 4 q x 8 h x 4 ch-groups(8ch). Per point: 4 tap loads
// (16 B each) issued back-to-back, then weighted fp32 accumulate.
// Writes s fp16 (outproj A-operand).
// ---------------------------------------------------------------------------
__global__ __launch_bounds__(128) void sample_f16(
    const _Float16* __restrict__ v,    // (B, L2, 256) fp16
    const float* __restrict__ qp,      // (BQ, 384): cols 0..255 offsets
    const float* __restrict__ attn,    // (BQ, 128)
    const float* __restrict__ ref,     // (BQ, 4)
    const float* __restrict__ vr,      // (B, 4, 2)
    const int*   __restrict__ vshape,  // (4, 2)
    const int*   __restrict__ vstart,  // (4,)
    _Float16* __restrict__ sout)       // (BQ, 256) fp16
{
    const int t  = threadIdx.x;
    const int q  = blockIdx.x * 4 + (t >> 5);
    const int h  = (t >> 2) & 7;
    const int c0 = (t & 3) * 8;
    const int b  = q >> 12;

    const float4 rw = *(const float4*)(ref + (size_t)q * 4);
    const float* op = qp + (size_t)q * 384 + h * 32;
    const float* ap = attn + (size_t)q * 128 + h * 16;

    float acc[8] = {};

#pragma unroll
    for (int l = 0; l < 4; ++l) {
        const int H = vshape[l * 2 + 0];
        const int W = vshape[l * 2 + 1];
        const int start = vstart[l];
        const float vrx = vr[(b * 4 + l) * 2 + 0];
        const float vry = vr[(b * 4 + l) * 2 + 1];
        const float fW = (float)W, fH = (float)H;
        const _Float16* vb = v + ((size_t)b * L2_LEN + start) * 256 + h * 32 + c0;
#pragma unroll
        for (int p = 0; p < 4; ++p) {
            const float a  = ap[l * 4 + p];
            const float ox = op[(l * 4 + p) * 2 + 0];
            const float oy = op[(l * 4 + p) * 2 + 1];
            const float x = (rw.x + ox * 0.125f * rw.z) * vrx * fW - 0.5f;
            const float y = (rw.y + oy * 0.125f * rw.w) * vry * fH - 0.5f;
            const float x0f = floorf(x), y0f = floorf(y);
            const float fx = x - x0f, fy = y - y0f;
            const int x0 = (int)x0f, y0 = (int)y0f;
            // validity folded into weights; clamped coords for address calc
            const float wx0 = (x0 >= 0 && x0 < W)         ? (1.0f - fx) : 0.0f;
            const float wx1 = (x0 + 1 >= 0 && x0 + 1 < W) ? fx          : 0.0f;
            const float wy0 = (y0 >= 0 && y0 < H)         ? (1.0f - fy) : 0.0f;
            const float wy1 = (y0 + 1 >= 0 && y0 + 1 < H) ? fy          : 0.0f;
            const int xc0 = min(max(x0, 0), W - 1),     xc1 = min(max(x0 + 1, 0), W - 1);
            const int yc0 = min(max(y0, 0), H - 1),     yc1 = min(max(y0 + 1, 0), H - 1);
            const float w00 = wx0 * wy0 * a, w01 = wx1 * wy0 * a;
            const float w10 = wx0 * wy1 * a, w11 = wx1 * wy1 * a;
            // batched tap loads (independent -> stay in flight together)
            const half8 g00 = *(const half8*)(vb + (size_t)(yc0 * W + xc0) * 256);
            const half8 g01 = *(const half8*)(vb + (size_t)(yc0 * W + xc1) * 256);
            const half8 g10 = *(const half8*)(vb + (size_t)(yc1 * W + xc0) * 256);
            const half8 g11 = *(const half8*)(vb + (size_t)(yc1 * W + xc1) * 256);
#pragma unroll
            for (int j = 0; j < 8; ++j)
                acc[j] += w00 * (float)g00[j] + w01 * (float)g01[j]
                        + w10 * (float)g10[j] + w11 * (float)g11[j];
        }
    }

    half8 o;
#pragma unroll
    for (int j = 0; j < 8; ++j) o[j] = (_Float16)acc[j];
    *(half8*)(sout + (size_t)q * 256 + h * 32 + c0) = o;
}

// ---------------------------------------------------------------------------
extern "C" void kernel_launch(void* const* d_in, const int* in_sizes, int n_in,
                              void* d_out, int out_size, void* d_ws, size_t ws_size,
                              hipStream_t stream)
{
    const float*         query    = (const float*)d_in[0];
    const float*         value    = (const float*)d_in[1];
    const int*           v_shape  = (const int*)d_in[2];
    const unsigned char* v_mask   = (const unsigned char*)d_in[3];
    const int*           v_start  = (const int*)d_in[4];
    const float*         v_ratios = (const float*)d_in[5];
    const float*         ref_w    = (const float*)d_in[6];
    const float*         Wo       = (const float*)d_in[7];
    const float*         bo       = (const float*)d_in[8];
    const float*         Wa       = (const float*)d_in[9];
    const float*         ba       = (const float*)d_in[10];
    const float*         Wv       = (const float*)d_in[11];
    const float*         bv       = (const float*)d_in[12];
    const float*         Wout     = (const float*)d_in[13];
    const float*         bout     = (const float*)d_in[14];

    float* out      = (float*)d_out;                      // (16384, 256)
    float* attn_out = out + (size_t)BQ_TOT * 256;         // (16384, 128)

    // ws layout (131,534,336 B total; fits 128 MiB)
    _Float16* Vf = (_Float16*)d_ws;                       // value fp16   (22282240)
    _Float16* vh = Vf + (size_t)4 * L2_LEN * 256;         // v=proj fp16  (22282240)
    _Float16* Qf = vh + (size_t)4 * L2_LEN * 256;         // query fp16   (4194304)
    _Float16* Sf = Qf + (size_t)BQ_TOT * 256;             // sampled fp16 (4194304)
    _Float16* Wp = Sf + (size_t)BQ_TOT * 256;             // weights fp16 (229376)
    float*    bp = (float*)(Wp + 229376);                 // biases fp32  (896)
    float*    qp = bp + 896;                              // off|logits   (16384*384 f32)

    // 1) input conversions
    cvt_f32_f16<<<2048, 256, 0, stream>>>(value, Vf, (4 * L2_LEN * 256) / 8);
    cvt_f32_f16<<<2048, 256, 0, stream>>>(query, Qf, (BQ_TOT * 256) / 8);
    cvt_weights<<<112, 256, 0, stream>>>(Wv, Wo, Wa, Wout, bv, bo, ba, bout, Wp, bp);
    // 2) value projection (+mask), fp16 out
    gemm_f16<true><<<dim3(680, 2), 256, 0, stream>>>(
        Vf, Wp, bp, 0, vh, 256, v_mask);
    // 3) fused offset+logits projection (N=384 = Wo(256)|Wa(128)), fp32 out
    gemm_f16<false><<<dim3(128, 3), 256, 0, stream>>>(
        Qf, Wp, bp, 256, qp, 384, nullptr);
    // 4) softmax on logits
    softmax_kernel<<<512, 256, 0, stream>>>(qp + 256, 384, attn_out, BQ_TOT * 8);
    // 5) sampling
    sample_f16<<<4096, 128, 0, stream>>>(
        vh, qp, attn_out, ref_w, v_ratios, v_shape, v_start, Sf);
    // 6) output projection, fp32 out
    gemm_f16<false><<<dim3(128, 2), 256, 0, stream>>>(
        Sf, Wp, bp, 640, out, 256, nullptr);
}

// Round 4
// 274.491 us; speedup vs baseline: 1.7883x; 1.0667x over previous
//
#include <hip/hip_runtime.h>
#include <cstdint>
#include <cstddef>

// ---------------------------------------------------------------------------
// MS-Deformable Attention forward, MI355X / gfx950 — round 4.
//  * conversions fused into GEMM staging (reg-stage f32->f16 -> LDS frag-major)
//  * vproj reads value ONCE (BM=128 x BN=256 tile, 8 waves)
//  * softmax fused into sampler; v stored HEAD-MAJOR (b,h,l2,32ch) fp16
//  * level geometry hardcoded (128/64/32/16 -> shift arithmetic)
// Launches: cvt_weights, vproj, qproj, sampler, outproj  (5 total)
// ---------------------------------------------------------------------------

#define L2_LEN 21760
#define BQ_TOT 16384

typedef __attribute__((ext_vector_type(8))) _Float16 half8;
typedef __attribute__((ext_vector_type(4))) float    f32x4;

__device__ __forceinline__ void glds16(const _Float16* g, _Float16* l) {
    __builtin_amdgcn_global_load_lds(
        (const __attribute__((address_space(1))) void*)g,
        (__attribute__((address_space(3))) void*)l, 16, 0, 0);
}
__device__ __forceinline__ half8 cvt8(float4 a, float4 b) {
    half8 h;
    h[0] = (_Float16)a.x; h[1] = (_Float16)a.y;
    h[2] = (_Float16)a.z; h[3] = (_Float16)a.w;
    h[4] = (_Float16)b.x; h[5] = (_Float16)b.y;
    h[6] = (_Float16)b.z; h[7] = (_Float16)b.w;
    return h;
}

// ---------------------------------------------------------------------------
// Pack [Wv | Wo | Wa | Wout] -> Wp fp16 (896 x 256), biases -> bp fp32 (896).
// ---------------------------------------------------------------------------
__global__ __launch_bounds__(256) void cvt_weights(
    const float* __restrict__ Wv, const float* __restrict__ Wo,
    const float* __restrict__ Wa, const float* __restrict__ Wout,
    const float* __restrict__ bv, const float* __restrict__ bo,
    const float* __restrict__ ba, const float* __restrict__ bout,
    _Float16* __restrict__ Wp, float* __restrict__ bp)
{
    const int gid = blockIdx.x * 256 + threadIdx.x;      // 0..28671 (8-el chunks)
    const float* src; int off8;
    if      (gid <  8192) { src = Wv;   off8 = gid;         }
    else if (gid < 16384) { src = Wo;   off8 = gid -  8192; }
    else if (gid < 20480) { src = Wa;   off8 = gid - 16384; }
    else                  { src = Wout; off8 = gid - 20480; }
    const float4 f0 = ((const float4*)src)[off8 * 2];
    const float4 f1 = ((const float4*)src)[off8 * 2 + 1];
    ((half8*)Wp)[gid] = cvt8(f0, f1);
    if (gid < 896) {
        float b;
        if      (gid < 256) b = bv[gid];
        else if (gid < 512) b = bo[gid - 256];
        else if (gid < 640) b = ba[gid - 512];
        else                b = bout[gid - 640];
        bp[gid] = b;
    }
}

// ---------------------------------------------------------------------------
// vproj: vh[(b,h,l2,32)] = (value @ Wv^T + bv) * !mask, fp16 head-major out.
// Tile 128M x 256N, K=256 (BK=32), 512 thr = 8 waves (2M x 4N), wave 64x64.
// A (f32): reg-staged+converted into frag-major LDS.  B: global_load_lds.
// Frag-major chunk u <-> (row=(u>>6)*16+(u&15), kgrp=(u>>4)&3); frag f =
// chunks [f*64, f*64+64), read at chunk f*64+lane (2 lanes/bank = free).
// ---------------------------------------------------------------------------
__global__ __launch_bounds__(512) void gemm_vproj(
    const float* __restrict__ A,        // (87040, 256) f32
    const _Float16* __restrict__ Wp,    // rows 0..255 = Wv
    const float* __restrict__ bp,
    _Float16* __restrict__ vh,          // (4, 8, 21760, 32) fp16
    const unsigned char* __restrict__ mask)
{
    __shared__ _Float16 As[4096];       // 128x32 frag-major (8 KiB)
    __shared__ _Float16 Bs[8192];       // 256x32 frag-major (16 KiB)

    const int t = threadIdx.x, lane = t & 63, wid = t >> 6;
    const int wm = wid >> 2, wn = wid & 3;
    const int bm = blockIdx.x;          // 680

    // A staging: thread t <-> chunk u=t: row=t>>2, kpart=t&3 (8 f32 = 32 B)
    const int ar = t >> 2, akp = t & 3;
    const float* Ag = A + (size_t)(bm * 128 + ar) * 256 + akp * 8;
    _Float16* Ad = &As[((ar >> 4) * 64 + akp * 16 + (ar & 15)) * 8];

    // B staging: 1024 chunks; wave stages [wid*128, wid*128+128) in 2 calls
    const int u0 = wid * 128 + lane, u1 = u0 + 64;
    const int br0 = ((u0 >> 6) << 4) + (u0 & 15), bk0 = ((u0 >> 4) & 3) * 8;
    const int br1 = ((u1 >> 6) << 4) + (u1 & 15), bk1 = ((u1 >> 4) & 3) * 8;
    const _Float16* Wg0 = Wp + (size_t)br0 * 256 + bk0;
    const _Float16* Wg1 = Wp + (size_t)br1 * 256 + bk1;
    _Float16* Bd0 = &Bs[(size_t)wid * 1024];
    _Float16* Bd1 = Bd0 + 512;

    f32x4 acc[4][4] = {};

    for (int kk = 0; kk < 256; kk += 32) {
        const float4 a0 = *(const float4*)(Ag + kk);
        const float4 a1 = *(const float4*)(Ag + kk + 4);
        __syncthreads();                     // prior frag reads done
        glds16(Wg0 + kk, Bd0);
        glds16(Wg1 + kk, Bd1);
        *(half8*)Ad = cvt8(a0, a1);
        __syncthreads();                     // drains glds (vmcnt) + ds_write
        half8 ah[4], bh[4];
#pragma unroll
        for (int x = 0; x < 4; ++x) {
            ah[x] = ((const half8*)As)[(wm * 4 + x) * 64 + lane];
            bh[x] = ((const half8*)Bs)[(wn * 4 + x) * 64 + lane];
        }
#pragma unroll
        for (int m = 0; m < 4; ++m)
#pragma unroll
            for (int n = 0; n < 4; ++n)
                acc[m][n] = __builtin_amdgcn_mfma_f32_16x16x32_f16(
                    ah[m], bh[n], acc[m][n], 0, 0, 0);
    }

    // epilogue: head-major write. b const per block (21760 = 170*128).
    const int b = bm / 170;
    const int l2b = (bm - b * 170) * 128;
    const int cl = lane & 15, rl = (lane >> 4) * 4;
#pragma unroll
    for (int m = 0; m < 4; ++m) {
        const int ro = wm * 64 + m * 16 + rl;         // row offset in tile
        float mz[4];
#pragma unroll
        for (int r = 0; r < 4; ++r)
            mz[r] = mask[bm * 128 + ro + r] ? 0.0f : 1.0f;
#pragma unroll
        for (int n = 0; n < 4; ++n) {
            const int col = wn * 64 + n * 16 + cl;    // 0..255
            const int h = col >> 5, c = col & 31;
            const float bb = bp[col];
            _Float16* dst = vh + ((size_t)(b * 8 + h) * L2_LEN + l2b + ro) * 32 + c;
#pragma unroll
            for (int r = 0; r < 4; ++r)
                dst[(size_t)r * 32] = (_Float16)((acc[m][n][r] + bb) * mz[r]);
        }
    }
}

// ---------------------------------------------------------------------------
// qproj / outproj: C f32 = A @ Wp[wrow0..]^T + bp[wrow0..].  Tile 128x128,
// 256 thr = 4 waves (2x2).  A_F32: A reg-staged f32->f16; else A fp16 via
// global_load_lds.
// ---------------------------------------------------------------------------
template<bool A_F32>
__global__ __launch_bounds__(256) void gemm_qo(
    const void* __restrict__ Av, const _Float16* __restrict__ Wp,
    const float* __restrict__ bp, int wrow0,
    float* __restrict__ C, int ldC)
{
    __shared__ _Float16 As[4096];   // 128x32
    __shared__ _Float16 Bs[4096];   // 128x32

    const int t = threadIdx.x, lane = t & 63, wid = t >> 6;
    const int wm = wid >> 1, wn = wid & 1;
    const int bm = blockIdx.x, bn = blockIdx.y;

    // B staging (512 chunks, 2 glds/wave)
    const int u0 = wid * 128 + lane, u1 = u0 + 64;
    const int br0 = ((u0 >> 6) << 4) + (u0 & 15), bk0 = ((u0 >> 4) & 3) * 8;
    const int br1 = ((u1 >> 6) << 4) + (u1 & 15), bk1 = ((u1 >> 4) & 3) * 8;
    const _Float16* Wg0 = Wp + (size_t)(wrow0 + bn * 128 + br0) * 256 + bk0;
    const _Float16* Wg1 = Wp + (size_t)(wrow0 + bn * 128 + br1) * 256 + bk1;
    _Float16* Bd0 = &Bs[(size_t)wid * 1024];
    _Float16* Bd1 = Bd0 + 512;

    // A staging
    const float*    Agf = nullptr; _Float16* Adf0 = nullptr; _Float16* Adf1 = nullptr;
    const _Float16* Agh0 = nullptr; const _Float16* Agh1 = nullptr;
    _Float16* Adh0 = nullptr; _Float16* Adh1 = nullptr;
    if (A_F32) {
        // thread t: row=t>>1, k-els [(t&1)*16, +16) = 64 B f32 -> 2 chunks
        const int r = t >> 1, kp = (t & 1) * 2;
        Agf  = (const float*)Av + (size_t)(bm * 128 + r) * 256 + kp * 8;
        Adf0 = &As[((r >> 4) * 64 + kp * 16 + (r & 15)) * 8];
        Adf1 = Adf0 + 128;   // chunk +16
    } else {
        Agh0 = (const _Float16*)Av + (size_t)(bm * 128 + br0) * 256 + bk0;
        Agh1 = (const _Float16*)Av + (size_t)(bm * 128 + br1) * 256 + bk1;
        Adh0 = &As[(size_t)wid * 1024];
        Adh1 = Adh0 + 512;
    }

    f32x4 acc[4][4] = {};

    for (int kk = 0; kk < 256; kk += 32) {
        float4 a0, a1, a2, a3;
        if (A_F32) {
            a0 = *(const float4*)(Agf + kk);      a1 = *(const float4*)(Agf + kk + 4);
            a2 = *(const float4*)(Agf + kk + 8);  a3 = *(const float4*)(Agf + kk + 12);
        }
        __syncthreads();
        glds16(Wg0 + kk, Bd0);
        glds16(Wg1 + kk, Bd1);
        if (A_F32) {
            *(half8*)Adf0 = cvt8(a0, a1);
            *(half8*)Adf1 = cvt8(a2, a3);
        } else {
            glds16(Agh0 + kk, Adh0);
            glds16(Agh1 + kk, Adh1);
        }
        __syncthreads();
        half8 ah[4], bh[4];
#pragma unroll
        for (int x = 0; x < 4; ++x) {
            ah[x] = ((const half8*)As)[(wm * 4 + x) * 64 + lane];
            bh[x] = ((const half8*)Bs)[(wn * 4 + x) * 64 + lane];
        }
#pragma unroll
        for (int m = 0; m < 4; ++m)
#pragma unroll
            for (int n = 0; n < 4; ++n)
                acc[m][n] = __builtin_amdgcn_mfma_f32_16x16x32_f16(
                    ah[m], bh[n], acc[m][n], 0, 0, 0);
    }

    const int rb = bm * 128 + wm * 64, cb = bn * 128 + wn * 64;
    const int cl = lane & 15, rl = (lane >> 4) * 4;
#pragma unroll
    for (int n = 0; n < 4; ++n) {
        const float bb = bp[wrow0 + cb + n * 16 + cl];
#pragma unroll
        for (int m = 0; m < 4; ++m)
#pragma unroll
            for (int r = 0; r < 4; ++r)
                C[(size_t)(rb + m * 16 + rl + r) * ldC + cb + n * 16 + cl] =
                    acc[m][n][r] + bb;
    }
}

// ---------------------------------------------------------------------------
// Sampler with fused softmax. Block 128 thr = 4 q x 8 h x 4 ch-groups(8).
// v head-major (b,h,l2,32) fp16; level geometry hardcoded; writes attn f32
// to d_out and sampled fp16 to Sf.
// ---------------------------------------------------------------------------
__global__ __launch_bounds__(128) void sample_fused(
    const _Float16* __restrict__ v,    // (4,8,21760,32) fp16
    const float* __restrict__ qp,      // (BQ,384): off(256) | logits(128)
    const float* __restrict__ ref,     // (BQ,4)
    const float* __restrict__ vr,      // (4,4,2)
    float* __restrict__ attn_out,      // (BQ,8,16) f32
    _Float16* __restrict__ sout)       // (BQ,256) fp16
{
    constexpr int HH[4] = {128, 64, 32, 16};
    constexpr int SS[4] = {0, 16384, 20480, 21504};

    const int t  = threadIdx.x;
    const int q  = blockIdx.x * 4 + (t >> 5);
    const int h  = (t >> 2) & 7;
    const int c0 = (t & 3) * 8;
    const int b  = q >> 12;

    // fused softmax over this (q,h)'s 16 logits (redundant across 4 threads)
    const float* lg = qp + (size_t)q * 384 + 256 + h * 16;
    const float4 l0 = ((const float4*)lg)[0], l1 = ((const float4*)lg)[1];
    const float4 l2 = ((const float4*)lg)[2], l3 = ((const float4*)lg)[3];
    float ap[16] = {l0.x, l0.y, l0.z, l0.w, l1.x, l1.y, l1.z, l1.w,
                    l2.x, l2.y, l2.z, l2.w, l3.x, l3.y, l3.z, l3.w};
    float mx = ap[0];
#pragma unroll
    for (int j = 1; j < 16; ++j) mx = fmaxf(mx, ap[j]);
    float sum = 0.0f;
#pragma unroll
    for (int j = 0; j < 16; ++j) { ap[j] = __expf(ap[j] - mx); sum += ap[j]; }
    const float inv = 1.0f / sum;
#pragma unroll
    for (int j = 0; j < 16; ++j) ap[j] *= inv;
    if (c0 == 0) {
        float4* ao = (float4*)(attn_out + ((size_t)q * 8 + h) * 16);
        ao[0] = make_float4(ap[0], ap[1], ap[2], ap[3]);
        ao[1] = make_float4(ap[4], ap[5], ap[6], ap[7]);
        ao[2] = make_float4(ap[8], ap[9], ap[10], ap[11]);
        ao[3] = make_float4(ap[12], ap[13], ap[14], ap[15]);
    }

    const float4 rw = *(const float4*)(ref + (size_t)q * 4);
    const float* op = qp + (size_t)q * 384 + h * 32;

    float acc[8] = {};

#pragma unroll
    for (int l = 0; l < 4; ++l) {
        const int HW = HH[l];                     // H == W per level
        const float fHW = (float)HW;
        const float vrx = vr[(b * 4 + l) * 2 + 0];
        const float vry = vr[(b * 4 + l) * 2 + 1];
        const _Float16* vb = v + ((size_t)(b * 8 + h) * L2_LEN + SS[l]) * 32 + c0;
#pragma unroll
        for (int p = 0; p < 4; ++p) {
            const float a  = ap[l * 4 + p];
            const float ox = op[(l * 4 + p) * 2 + 0];
            const float oy = op[(l * 4 + p) * 2 + 1];
            const float x = (rw.x + ox * 0.125f * rw.z) * vrx * fHW - 0.5f;
            const float y = (rw.y + oy * 0.125f * rw.w) * vry * fHW - 0.5f;
            const float x0f = floorf(x), y0f = floorf(y);
            const float fx = x - x0f, fy = y - y0f;
            const int x0 = (int)x0f, y0 = (int)y0f;
            const float wx0 = (x0 >= 0 && x0 < HW)         ? (1.0f - fx) : 0.0f;
            const float wx1 = (x0 + 1 >= 0 && x0 + 1 < HW) ? fx          : 0.0f;
            const float wy0 = (y0 >= 0 && y0 < HW)         ? (1.0f - fy) : 0.0f;
            const float wy1 = (y0 + 1 >= 0 && y0 + 1 < HW) ? fy          : 0.0f;
            const int xc0 = min(max(x0, 0), HW - 1), xc1 = min(max(x0 + 1, 0), HW - 1);
            const int yc0 = min(max(y0, 0), HW - 1), yc1 = min(max(y0 + 1, 0), HW - 1);
            const float w00 = wx0 * wy0 * a, w01 = wx1 * wy0 * a;
            const float w10 = wx0 * wy1 * a, w11 = wx1 * wy1 * a;
            const half8 g00 = *(const half8*)(vb + (size_t)(yc0 * HW + xc0) * 32);
            const half8 g01 = *(const half8*)(vb + (size_t)(yc0 * HW + xc1) * 32);
            const half8 g10 = *(const half8*)(vb + (size_t)(yc1 * HW + xc0) * 32);
            const half8 g11 = *(const half8*)(vb + (size_t)(yc1 * HW + xc1) * 32);
#pragma unroll
            for (int j = 0; j < 8; ++j)
                acc[j] += w00 * (float)g00[j] + w01 * (float)g01[j]
                        + w10 * (float)g10[j] + w11 * (float)g11[j];
        }
    }

    half8 o;
#pragma unroll
    for (int j = 0; j < 8; ++j) o[j] = (_Float16)acc[j];
    *(half8*)(sout + (size_t)q * 256 + h * 32 + c0) = o;
}

// ---------------------------------------------------------------------------
extern "C" void kernel_launch(void* const* d_in, const int* in_sizes, int n_in,
                              void* d_out, int out_size, void* d_ws, size_t ws_size,
                              hipStream_t stream)
{
    const float*         query    = (const float*)d_in[0];
    const float*         value    = (const float*)d_in[1];
    const unsigned char* v_mask   = (const unsigned char*)d_in[3];
    const float*         v_ratios = (const float*)d_in[5];
    const float*         ref_w    = (const float*)d_in[6];
    const float*         Wo       = (const float*)d_in[7];
    const float*         bo       = (const float*)d_in[8];
    const float*         Wa       = (const float*)d_in[9];
    const float*         ba       = (const float*)d_in[10];
    const float*         Wv       = (const float*)d_in[11];
    const float*         bv       = (const float*)d_in[12];
    const float*         Wout     = (const float*)d_in[13];
    const float*         bout     = (const float*)d_in[14];

    float* out      = (float*)d_out;                      // (16384, 256)
    float* attn_out = out + (size_t)BQ_TOT * 256;         // (16384, 128)

    _Float16* Wp = (_Float16*)d_ws;                       // 896x256 fp16
    float*    bp = (float*)(Wp + 896 * 256);              // 896 f32
    float*    qp = bp + 896;                              // (16384,384) f32
    _Float16* vh = (_Float16*)(qp + (size_t)BQ_TOT * 384);// (4,8,21760,32) fp16
    _Float16* Sf = vh + (size_t)4 * L2_LEN * 256;         // (16384,256) fp16

    // 1) weights -> fp16
    cvt_weights<<<112, 256, 0, stream>>>(Wv, Wo, Wa, Wout, bv, bo, ba, bout, Wp, bp);
    // 2) value projection (fused f32->f16 staging; head-major fp16 out; mask)
    gemm_vproj<<<680, 512, 0, stream>>>(value, Wp, bp, vh, v_mask);
    // 3) fused offset+logits projection (N=384 from Wp rows 256..639)
    gemm_qo<true><<<dim3(128, 3), 256, 0, stream>>>(query, Wp, bp, 256, qp, 384);
    // 4) sampler (+fused softmax -> attn_out)
    sample_fused<<<4096, 128, 0, stream>>>(vh, qp, ref_w, v_ratios, attn_out, Sf);
    // 5) output projection (A = Sf fp16, Wp rows 640..895)
    gemm_qo<false><<<dim3(128, 2), 256, 0, stream>>>(Sf, Wp, bp, 640, out, 256);
}